// Round 4
// baseline (847.106 us; speedup 1.0000x reference)
//
#include <hip/hip_runtime.h>
#include <math.h>

// SwinTransformerBlock3D: B=2, grid(16,64,64) -> L=65536, C=96, H=6, hd=16,
// win 4^3 -> N=64 tokens/window, shift (2,2,2), 2048 windows, MLP hidden 384.
// All I/O float32.

// ---------------- Kernel A: LN1 + window attention + proj + residual ----------------
__global__ __launch_bounds__(256, 1)
void swin_attn_kernel(const float* __restrict__ x,
                      const float* __restrict__ n1g, const float* __restrict__ n1b,
                      const float* __restrict__ qkvw, const float* __restrict__ qkvb,
                      const float* __restrict__ projw, const float* __restrict__ projb,
                      const float* __restrict__ btab,
                      float* __restrict__ y)
{
    __shared__ __align__(16) float hT[96 * 66];      // h^T [ch][tok], later o^T
    __shared__ __align__(16) float q_s[6 * 64 * 20]; // q[head][tok][d], pre-scaled
    __shared__ __align__(16) float kT[6 * 16 * 68];  // k^T [head][d][tok]
    __shared__ __align__(16) float v_s[6 * 64 * 20]; // v[head][tok][d]
    __shared__ __align__(16) float wbuf[96 * 96];    // weight tile; aliased as P [64][68]

    const int tid = threadIdx.x;
    const int wid = blockIdx.x;
    const int bb = wid >> 10;
    const int wi = (wid >> 8) & 3;
    const int wx = (wid >> 4) & 15;
    const int wt = wid & 15;

    // ---- phase 1: gather (roll -2) + LayerNorm1 -> hT ----
    {
        const int n = tid >> 2, p = tid & 3;
        const int a = n >> 4, c = (n >> 2) & 3, e = n & 3;
        const int gi = (wi * 4 + a + 2) & 15;
        const int gx = (wx * 4 + c + 2) & 63;
        const int gt = (wt * 4 + e + 2) & 63;
        const int l = (gi << 12) + (gx << 6) + gt;
        const float* src = x + ((size_t)bb * 65536 + l) * 96 + p * 24;
        float v[24];
        #pragma unroll
        for (int i = 0; i < 6; ++i) {
            const float4 t = *(const float4*)(src + i * 4);
            v[i*4+0] = t.x; v[i*4+1] = t.y; v[i*4+2] = t.z; v[i*4+3] = t.w;
        }
        float s = 0.f, ss = 0.f;
        #pragma unroll
        for (int i = 0; i < 24; ++i) { s += v[i]; ss += v[i] * v[i]; }
        s  += __shfl_xor(s, 1);  s  += __shfl_xor(s, 2);
        ss += __shfl_xor(ss, 1); ss += __shfl_xor(ss, 2);
        const float mean = s * (1.f / 96.f);
        const float rstd = rsqrtf(ss * (1.f / 96.f) - mean * mean + 1e-5f);
        #pragma unroll
        for (int i = 0; i < 24; ++i) {
            const int ch = p * 24 + i;
            hT[ch * 66 + n] = (v[i] - mean) * rstd * n1g[ch] + n1b[ch];
        }
    }
    __syncthreads();

    // ---- phase 2: QKV = h @ qkv_w + qkv_b (3 tiles of 96 cols) ----
    {
        const int pair = tid >> 3, jg = tid & 7;
        const int n0 = pair * 2;
        for (int jt = 0; jt < 3; ++jt) {
            if (jt) __syncthreads();
            #pragma unroll
            for (int i = 0; i < 36; ++i) {
                const int idx = tid + i * 256;
                const int r = idx / 96, cc = idx - r * 96;
                wbuf[idx] = qkvw[r * 288 + jt * 96 + cc];
            }
            __syncthreads();
            float acc[2][12];
            #pragma unroll
            for (int j = 0; j < 12; ++j) { acc[0][j] = 0.f; acc[1][j] = 0.f; }
            #pragma unroll 4
            for (int k = 0; k < 96; ++k) {
                const float2 h2 = *(const float2*)&hT[k * 66 + n0];
                const float* wr = &wbuf[k * 96 + jg * 12];
                const float4 wa = *(const float4*)(wr + 0);
                const float4 wb = *(const float4*)(wr + 4);
                const float4 wc = *(const float4*)(wr + 8);
                const float w[12] = {wa.x, wa.y, wa.z, wa.w,
                                     wb.x, wb.y, wb.z, wb.w,
                                     wc.x, wc.y, wc.z, wc.w};
                #pragma unroll
                for (int j = 0; j < 12; ++j) {
                    acc[0][j] = fmaf(h2.x, w[j], acc[0][j]);
                    acc[1][j] = fmaf(h2.y, w[j], acc[1][j]);
                }
            }
            #pragma unroll
            for (int j = 0; j < 12; ++j) {
                const int rem = jg * 12 + j;    // 0..95 within tile
                const int hh = rem >> 4, d = rem & 15;
                const float bias = qkvb[jt * 96 + rem];
                const float v0 = acc[0][j] + bias;
                const float v1 = acc[1][j] + bias;
                if (jt == 0) {
                    q_s[(hh * 64 + n0) * 20 + d]       = v0 * 0.25f;  // * hd^-0.5
                    q_s[(hh * 64 + n0 + 1) * 20 + d]   = v1 * 0.25f;
                } else if (jt == 1) {
                    kT[(hh * 16 + d) * 68 + n0]        = v0;
                    kT[(hh * 16 + d) * 68 + n0 + 1]    = v1;
                } else {
                    v_s[(hh * 64 + n0) * 20 + d]       = v0;
                    v_s[(hh * 64 + n0 + 1) * 20 + d]   = v1;
                }
            }
        }
    }
    __syncthreads();

    // ---- phase 3: attention per head (scores + softmax in registers) ----
    {
        const int n = tid >> 2, p = tid & 3;
        const int a1 = n >> 4, c1 = (n >> 2) & 3, e1 = n & 3;
        int relidx[16];
        #pragma unroll
        for (int mm = 0; mm < 16; ++mm) {
            const int m = p * 16 + mm;
            const int a2 = m >> 4, c2 = (m >> 2) & 3, e2 = m & 3;
            relidx[mm] = ((a1 - a2 + 3) * 7 + (c1 - c2 + 3)) * 7 + (e1 - e2 + 3);
        }
        float* pbuf = wbuf;  // [64][68]
        for (int hd = 0; hd < 6; ++hd) {
            float qd[16];
            #pragma unroll
            for (int i = 0; i < 4; ++i)
                *(float4*)&qd[i*4] = *(const float4*)&q_s[(hd * 64 + n) * 20 + i * 4];
            float sc[16];
            #pragma unroll
            for (int mm = 0; mm < 16; ++mm) sc[mm] = btab[relidx[mm] * 6 + hd];
            #pragma unroll 4
            for (int d = 0; d < 16; ++d) {
                const float* kr = &kT[(hd * 16 + d) * 68 + p * 16];
                const float4 k0 = *(const float4*)(kr + 0);
                const float4 k1 = *(const float4*)(kr + 4);
                const float4 k2 = *(const float4*)(kr + 8);
                const float4 k3 = *(const float4*)(kr + 12);
                const float kv[16] = {k0.x,k0.y,k0.z,k0.w, k1.x,k1.y,k1.z,k1.w,
                                      k2.x,k2.y,k2.z,k2.w, k3.x,k3.y,k3.z,k3.w};
                const float qv = qd[d];
                #pragma unroll
                for (int mm = 0; mm < 16; ++mm) sc[mm] = fmaf(qv, kv[mm], sc[mm]);
            }
            float mx = sc[0];
            #pragma unroll
            for (int mm = 1; mm < 16; ++mm) mx = fmaxf(mx, sc[mm]);
            mx = fmaxf(mx, __shfl_xor(mx, 1));
            mx = fmaxf(mx, __shfl_xor(mx, 2));
            float sum = 0.f;
            #pragma unroll
            for (int mm = 0; mm < 16; ++mm) { sc[mm] = __expf(sc[mm] - mx); sum += sc[mm]; }
            sum += __shfl_xor(sum, 1);
            sum += __shfl_xor(sum, 2);
            const float inv = 1.f / sum;
            #pragma unroll
            for (int mm4 = 0; mm4 < 4; ++mm4) {
                const float4 t = make_float4(sc[mm4*4+0]*inv, sc[mm4*4+1]*inv,
                                             sc[mm4*4+2]*inv, sc[mm4*4+3]*inv);
                *(float4*)&pbuf[n * 68 + p * 16 + mm4 * 4] = t;
            }
            __syncthreads();
            // PV: o[n][d], d = p*4..p*4+3
            float4 o4 = make_float4(0.f, 0.f, 0.f, 0.f);
            #pragma unroll 4
            for (int m4 = 0; m4 < 16; ++m4) {
                const float4 pv4 = *(const float4*)&pbuf[n * 68 + m4 * 4];
                const float pv[4] = {pv4.x, pv4.y, pv4.z, pv4.w};
                #pragma unroll
                for (int q = 0; q < 4; ++q) {
                    const float4 v4 = *(const float4*)&v_s[(hd * 64 + m4 * 4 + q) * 20 + p * 4];
                    o4.x = fmaf(pv[q], v4.x, o4.x);
                    o4.y = fmaf(pv[q], v4.y, o4.y);
                    o4.z = fmaf(pv[q], v4.z, o4.z);
                    o4.w = fmaf(pv[q], v4.w, o4.w);
                }
            }
            const int cb = hd * 16 + p * 4;
            hT[(cb + 0) * 66 + n] = o4.x;   // o^T reuses hT
            hT[(cb + 1) * 66 + n] = o4.y;
            hT[(cb + 2) * 66 + n] = o4.z;
            hT[(cb + 3) * 66 + n] = o4.w;
            __syncthreads();
        }
    }

    // ---- phase 4: proj + residual -> y ----
    #pragma unroll
    for (int i = 0; i < 36; ++i) {
        const int idx = tid + i * 256;
        wbuf[idx] = projw[idx];   // [96][96] contiguous
    }
    __syncthreads();
    {
        const int pair = tid >> 3, jg = tid & 7;
        const int n0 = pair * 2;
        float acc[2][12];
        #pragma unroll
        for (int j = 0; j < 12; ++j) { acc[0][j] = 0.f; acc[1][j] = 0.f; }
        #pragma unroll 4
        for (int k = 0; k < 96; ++k) {
            const float2 o2 = *(const float2*)&hT[k * 66 + n0];
            const float* wr = &wbuf[k * 96 + jg * 12];
            const float4 wa = *(const float4*)(wr + 0);
            const float4 wb = *(const float4*)(wr + 4);
            const float4 wc = *(const float4*)(wr + 8);
            const float w[12] = {wa.x, wa.y, wa.z, wa.w,
                                 wb.x, wb.y, wb.z, wb.w,
                                 wc.x, wc.y, wc.z, wc.w};
            #pragma unroll
            for (int j = 0; j < 12; ++j) {
                acc[0][j] = fmaf(o2.x, w[j], acc[0][j]);
                acc[1][j] = fmaf(o2.y, w[j], acc[1][j]);
            }
        }
        #pragma unroll
        for (int i = 0; i < 2; ++i) {
            const int n = n0 + i;
            const int a = n >> 4, c = (n >> 2) & 3, e = n & 3;
            const int gi = (wi * 4 + a + 2) & 15;
            const int gx = (wx * 4 + c + 2) & 63;
            const int gt = (wt * 4 + e + 2) & 63;
            const int l = (gi << 12) + (gx << 6) + gt;
            const size_t base = ((size_t)bb * 65536 + l) * 96 + jg * 12;
            #pragma unroll
            for (int jq = 0; jq < 3; ++jq) {
                const float4 xv = *(const float4*)(x + base + jq * 4);
                float4 r;
                r.x = xv.x + acc[i][jq*4+0] + projb[jg*12 + jq*4+0];
                r.y = xv.y + acc[i][jq*4+1] + projb[jg*12 + jq*4+1];
                r.z = xv.z + acc[i][jq*4+2] + projb[jg*12 + jq*4+2];
                r.w = xv.w + acc[i][jq*4+3] + projb[jg*12 + jq*4+3];
                *(float4*)(y + base + jq * 4) = r;
            }
        }
    }
}

// ---------------- Kernel B: LN2 + MLP (gelu) + residual, in-place on y ----------------
__global__ __launch_bounds__(256, 1)
void swin_mlp_kernel(const float* __restrict__ y,
                     const float* __restrict__ n2g, const float* __restrict__ n2b,
                     const float* __restrict__ w1, const float* __restrict__ b1,
                     const float* __restrict__ w2, const float* __restrict__ b2,
                     float* __restrict__ out)
{
    __shared__ __align__(16) float h2T[96 * 132];  // LN2(y)^T [ch][tok]
    __shared__ __align__(16) float t1T[96 * 132];  // gelu tile^T [k][tok]
    __shared__ __align__(16) float wbuf[96 * 96];

    const int tid = threadIdx.x;
    const size_t tok0 = (size_t)blockIdx.x * 128;

    // ---- phase 1: LayerNorm2 -> h2T ----
    {
        const int tk = tid >> 1, half = tid & 1;
        const float* src = y + (tok0 + tk) * 96 + half * 48;
        float v[48];
        #pragma unroll
        for (int i = 0; i < 12; ++i) {
            const float4 t = *(const float4*)(src + i * 4);
            v[i*4+0]=t.x; v[i*4+1]=t.y; v[i*4+2]=t.z; v[i*4+3]=t.w;
        }
        float s = 0.f, ss = 0.f;
        #pragma unroll
        for (int i = 0; i < 48; ++i) { s += v[i]; ss += v[i]*v[i]; }
        s += __shfl_xor(s, 1); ss += __shfl_xor(ss, 1);
        const float mean = s * (1.f/96.f);
        const float rstd = rsqrtf(ss * (1.f/96.f) - mean*mean + 1e-5f);
        #pragma unroll
        for (int i = 0; i < 48; ++i) {
            const int ch = half * 48 + i;
            h2T[ch * 132 + tk] = (v[i]-mean)*rstd*n2g[ch] + n2b[ch];
        }
    }
    __syncthreads();

    const int tq = tid >> 3, jg = tid & 7;
    const int n0 = tq * 4;
    float acc2[4][12];
    #pragma unroll
    for (int i = 0; i < 4; ++i)
        #pragma unroll
        for (int j = 0; j < 12; ++j) acc2[i][j] = 0.f;

    for (int jt = 0; jt < 4; ++jt) {
        if (jt) __syncthreads();
        // stage W1 tile [96 k][96 j]
        #pragma unroll
        for (int i = 0; i < 36; ++i) {
            const int idx = tid + i * 256;
            const int r = idx / 96, cc = idx - r * 96;
            wbuf[idx] = w1[r * 384 + jt * 96 + cc];
        }
        __syncthreads();
        // layer 1 + gelu -> t1T
        {
            float a1[4][12];
            #pragma unroll
            for (int i = 0; i < 4; ++i)
                #pragma unroll
                for (int j = 0; j < 12; ++j) a1[i][j] = 0.f;
            #pragma unroll 2
            for (int k = 0; k < 96; ++k) {
                const float4 h4 = *(const float4*)&h2T[k * 132 + n0];
                const float hv[4] = {h4.x, h4.y, h4.z, h4.w};
                const float* wr = &wbuf[k * 96 + jg * 12];
                const float4 wa = *(const float4*)(wr + 0);
                const float4 wb = *(const float4*)(wr + 4);
                const float4 wc = *(const float4*)(wr + 8);
                const float w[12] = {wa.x, wa.y, wa.z, wa.w,
                                     wb.x, wb.y, wb.z, wb.w,
                                     wc.x, wc.y, wc.z, wc.w};
                #pragma unroll
                for (int i = 0; i < 4; ++i)
                    #pragma unroll
                    for (int j = 0; j < 12; ++j)
                        a1[i][j] = fmaf(hv[i], w[j], a1[i][j]);
            }
            #pragma unroll
            for (int j = 0; j < 12; ++j) {
                const float bv = b1[jt * 96 + jg * 12 + j];
                #pragma unroll
                for (int i = 0; i < 4; ++i) {
                    float t = a1[i][j] + bv;
                    t = 0.5f * t * (1.f + erff(t * 0.70710678118654752f));  // exact gelu
                    t1T[(jg * 12 + j) * 132 + n0 + i] = t;
                }
            }
        }
        __syncthreads();
        // stage W2 tile [96 k][96 c]
        #pragma unroll
        for (int i = 0; i < 36; ++i) {
            const int idx = tid + i * 256;
            const int r = idx / 96, cc = idx - r * 96;
            wbuf[idx] = w2[(jt * 96 + r) * 96 + cc];
        }
        __syncthreads();
        // layer 2 accumulate
        #pragma unroll 2
        for (int k = 0; k < 96; ++k) {
            const float4 t4 = *(const float4*)&t1T[k * 132 + n0];
            const float tv[4] = {t4.x, t4.y, t4.z, t4.w};
            const float* wr = &wbuf[k * 96 + jg * 12];
            const float4 wa = *(const float4*)(wr + 0);
            const float4 wb = *(const float4*)(wr + 4);
            const float4 wc = *(const float4*)(wr + 8);
            const float w[12] = {wa.x, wa.y, wa.z, wa.w,
                                 wb.x, wb.y, wb.z, wb.w,
                                 wc.x, wc.y, wc.z, wc.w};
            #pragma unroll
            for (int i = 0; i < 4; ++i)
                #pragma unroll
                for (int j = 0; j < 12; ++j)
                    acc2[i][j] = fmaf(tv[i], w[j], acc2[i][j]);
        }
    }

    // ---- epilogue: out = y + mlp ----
    #pragma unroll
    for (int i = 0; i < 4; ++i) {
        const size_t base = (tok0 + n0 + i) * 96 + jg * 12;
        #pragma unroll
        for (int jq = 0; jq < 3; ++jq) {
            const float4 yv = *(const float4*)(y + base + jq * 4);
            float4 r;
            r.x = yv.x + acc2[i][jq*4+0] + b2[jg*12 + jq*4+0];
            r.y = yv.y + acc2[i][jq*4+1] + b2[jg*12 + jq*4+1];
            r.z = yv.z + acc2[i][jq*4+2] + b2[jg*12 + jq*4+2];
            r.w = yv.w + acc2[i][jq*4+3] + b2[jg*12 + jq*4+3];
            *(float4*)(out + base + jq * 4) = r;
        }
    }
}

extern "C" void kernel_launch(void* const* d_in, const int* in_sizes, int n_in,
                              void* d_out, int out_size, void* d_ws, size_t ws_size,
                              hipStream_t stream) {
    (void)in_sizes; (void)n_in; (void)d_ws; (void)ws_size; (void)out_size;
    const float* x     = (const float*)d_in[0];
    const float* n1g   = (const float*)d_in[1];
    const float* n1b   = (const float*)d_in[2];
    const float* qkvw  = (const float*)d_in[3];
    const float* qkvb  = (const float*)d_in[4];
    const float* projw = (const float*)d_in[5];
    const float* projb = (const float*)d_in[6];
    const float* btab  = (const float*)d_in[7];
    const float* n2g   = (const float*)d_in[8];
    const float* n2b   = (const float*)d_in[9];
    const float* w1    = (const float*)d_in[10];
    const float* b1    = (const float*)d_in[11];
    const float* w2    = (const float*)d_in[12];
    const float* b2    = (const float*)d_in[13];
    float* out = (float*)d_out;

    swin_attn_kernel<<<2048, 256, 0, stream>>>(x, n1g, n1b, qkvw, qkvb,
                                               projw, projb, btab, out);
    swin_mlp_kernel<<<1024, 256, 0, stream>>>(out, n2g, n2b, w1, b1, w2, b2, out);
}